// Round 4
// baseline (259.718 us; speedup 1.0000x reference)
//
#include <hip/hip_runtime.h>
#include <math.h>

#define T_ 512

typedef _Float16 half8 __attribute__((ext_vector_type(8)));
typedef _Float16 half4 __attribute__((ext_vector_type(4)));
typedef float f32x4 __attribute__((ext_vector_type(4)));

// tanh(a)*sigmoid(b) = ((e^2a - 1) * e^b) / ((e^2a + 1) * (e^b + 1))
// single raw v_rcp instead of two full-precision divides.
__device__ __forceinline__ float ts_act(float a, float b) {
    float e2a = __expf(a + a);
    float eb  = __expf(b);
    float num = (e2a - 1.0f) * eb;
    float den = (e2a + 1.0f) * (eb + 1.0f);
    return num * __builtin_amdgcn_rcpf(den);
}

__device__ __forceinline__ half4 pack4(f32x4 v) {
    half4 h;
    h[0] = (_Float16)v[0]; h[1] = (_Float16)v[1];
    h[2] = (_Float16)v[2]; h[3] = (_Float16)v[3];
    return h;
}

// ---------------------------------------------------------------------------
// Prep fragment buffers in d_ws.
//  AF  [16384 f16] : adjacency, frag((it*4+kt))[lane][j] = A[it*16+(L&15)][kt*32+(L>>4)*8+j]
//  W32 [ 8192 f16] : K=32 folded conv mats (l*2+branch), 0..7
//                    frag idx (mat*2+ct)*64+L, slot j: W[k=(L>>4)*8+j][ct*16+(L&15)]
//  W16 [15360 f16] : K=16 mats: l*3+{0:gw,1:rw,2:sw} (0..11), 12:w1, 13:w2(pad), 14:winit16
//                    frag idx (mat*4+ks*2+ct)*64+L, slot i: W[ks*16+(L>>4)*4+i][ct*16+(L&15)]
//  BIAS[512 f32]   : pv-resolved conv biases: [(l*2+pv)*2+br]*32+n
// total idx = 16384+8192+15360+512 = 40448 = 158*256 (bytes: 79872 + 2048 = 81920)
// ---------------------------------------------------------------------------
__global__ __launch_bounds__(256) void k_prep(
    const float* __restrict__ A,     const float* __restrict__ in_w,
    const float* __restrict__ in_b,
    const float* __restrict__ ct_w,  const float* __restrict__ ct_b,
    const float* __restrict__ cs_w,  const float* __restrict__ cs_b,
    const float* __restrict__ gcn_w, const float* __restrict__ res_w,
    const float* __restrict__ skip_w,
    const float* __restrict__ out1_w,const float* __restrict__ out2_w,
    _Float16* __restrict__ FR, float* __restrict__ BIAS)
{
    int idx = blockIdx.x * 256 + threadIdx.x;
    if (idx < 16384) {
        int j = idx & 7, L = (idx >> 3) & 63, tile = idx >> 9;
        int it = tile >> 2, kt = tile & 3;
        FR[idx] = (_Float16)A[(it * 16 + (L & 15)) * 128 + kt * 32 + (L >> 4) * 8 + j];
    } else if (idx < 24576) {
        int e = idx - 16384;
        int j = e & 7, L = (e >> 3) & 63, ct = (e >> 9) & 1, mat = e >> 10;   // 0..7
        int k = (L >> 4) * 8 + j, col = ct * 16 + (L & 15);
        int l = mat >> 1, br = mat & 1;
        const float* tw = (br ? cs_w : ct_w) + l * 2048;
        int bro = br * 32;
        float v = 0.f;
        if (k < 16) { for (int c = 0; c < 32; ++c) v += in_w[k*96 + bro + c] * tw[c*32 + col]; }
        else        { for (int c = 0; c < 32; ++c) v += in_w[(k-16)*96 + bro + c] * tw[1024 + c*32 + col]; }
        FR[idx] = (_Float16)v;
    } else if (idx < 39936) {
        int e = idx - 24576;
        int i = e & 3, L = (e >> 2) & 63, ct = (e >> 8) & 1, ks = (e >> 9) & 1, mat = e >> 10; // 0..14
        int k = ks * 16 + (L >> 4) * 4 + i, col = ct * 16 + (L & 15);
        float v;
        if (mat < 12) {
            int l = mat / 3, r = mat - l * 3;
            const float* W = (r == 0) ? gcn_w : (r == 1) ? res_w : skip_w;
            v = W[l * 1024 + k * 32 + col];
        } else if (mat == 12) v = out1_w[k * 32 + col];
        else if (mat == 13)   v = (ct == 0) ? out2_w[k * 16 + (L & 15)] : 0.f;
        else                  v = (ks == 0) ? in_w[k * 96 + 64 + col] : 0.f;   // winit K=16
        FR[idx] = (_Float16)v;
    } else if (idx < 40448) {
        // pv-resolved conv biases: e = l*128 + pvi*64 + br*32 + n
        int e = idx - 39936;
        int n = e & 31, br = (e >> 5) & 1, pvi = (e >> 6) & 1, l = e >> 7;
        const float* W  = br ? cs_w : ct_w;
        const float* bb = br ? cs_b : ct_b;
        int ibo = br * 32;
        float v = bb[l * 32 + n];
        for (int c = 0; c < 32; ++c) v += in_b[ibo + c] * W[l*2048 + 1024 + c*32 + n]; // cur tap
        if (pvi)
            for (int c = 0; c < 32; ++c) v += in_b[ibo + c] * W[l*2048 + c*32 + n];    // prev tap
        BIAS[e] = v;
    }
}

// ---------------------------------------------------------------------------
// Fused net, timestep-PAIRED: one block per (b, t0=2*tp), 512 threads.
// Waves 0-3 compute time t0 (node tiles 0-3); waves 4-7 compute t0+1.
// The pair shares one Pld with the 8-slab union {t0-8,t0-7,t0-4,t0-3,
// t0-2,t0-1,t0,t0+1}: prev-slab(ts,l) = ts + {5,4,2,0}[l], cur = 6+ts.
// Staging cost per output drops 2.5x; 8 independent waves per barrier
// group double the latency-hiding pool. Per-wave registers unchanged.
// ---------------------------------------------------------------------------
__global__ __launch_bounds__(512, 4) void k_fused(
    const float* __restrict__ X,
    const _Float16* __restrict__ FR,
    const float* __restrict__ BIAS,
    const float* __restrict__ in_b,
    const float* __restrict__ gcn_b,
    const float* __restrict__ res_b,
    const float* __restrict__ skip_b,
    const float* __restrict__ b1,
    const float* __restrict__ b2,
    float* __restrict__ out)
{
    __shared__ _Float16 Pld[128 * 136];        // [node][slab0..7 (16 each)|pad8]
    __shared__ _Float16 xsT[2][2][32 * 136];   // [ts][pingpong][chan][node+pad8]

    const int bx = blockIdx.x;
    const int btp = ((bx & 7) << 8) | (bx >> 3);    // XCD j <- batch j
    const int b = btp >> 8, t0 = (btp & 255) * 2;
    const int tid = threadIdx.x, lane = tid & 63;
    const int g = tid >> 6, ts = g >> 2, ws = g & 3;
    const int t = t0 + ts;                          // this wave's timestep
    const int lm = lane & 15, kb = lane >> 4;
    const int R = ws * 32;
    const int row = lane >> 1, ch = lane & 1;

    const half8* AFv  = (const half8*)FR;
    const half8* W32v = (const half8*)(FR + 16384);
    const half4* W16v = (const half4*)(FR + 24576);
    const f32x4 zero4 = {0.f, 0.f, 0.f, 0.f};

    // ---- stage this group's 4 slabs of the 8-slab union ----
    // slab s holds time t0 + toff[s], toff = {-8,-7,-4,-3,-2,-1,0,+1}
    {
        const int toff[8] = {-8, -7, -4, -3, -2, -1, 0, 1};
        const size_t nrow = (size_t)(b * 128 + R + row) * T_;
#pragma unroll
        for (int sl = 0; sl < 4; ++sl) {
            const int slab = ts * 4 + sl;
            const int tt = t0 + toff[slab];
            half8 hv = {0,0,0,0,0,0,0,0};
            if (tt >= 0) {
                const float4* xp = (const float4*)(X + (nrow + tt) * 16 + ch * 8);
                float4 u0 = xp[0], u1 = xp[1];
                hv[0]=(_Float16)u0.x; hv[1]=(_Float16)u0.y; hv[2]=(_Float16)u0.z; hv[3]=(_Float16)u0.w;
                hv[4]=(_Float16)u1.x; hv[5]=(_Float16)u1.y; hv[6]=(_Float16)u1.z; hv[7]=(_Float16)u1.w;
            }
            *(half8*)&Pld[(R + row) * 136 + slab * 16 + ch * 8] = hv;
        }
    }

    // ---- xres init: K=16 MFMA straight from registers (true coords) ----
    f32x4 xm[2][2], skT[2][2];
    {
        const size_t base = (size_t)(b * 512 + t) * 128;
        const float4 x0 = *(const float4*)(X + (base + R + lm) * 16 + kb * 4);
        const float4 x1 = *(const float4*)(X + (base + R + 16 + lm) * 16 + kb * 4);
        half4 p0, p1;
        p0[0]=(_Float16)x0.x; p0[1]=(_Float16)x0.y; p0[2]=(_Float16)x0.z; p0[3]=(_Float16)x0.w;
        p1[0]=(_Float16)x1.x; p1[1]=(_Float16)x1.y; p1[2]=(_Float16)x1.z; p1[3]=(_Float16)x1.w;
#pragma unroll
        for (int f = 0; f < 2; ++f) {
            half4 wi = W16v[(56 + f) * 64 + lane];          // winit mat 14, ks=0
            float bi = in_b[64 + f * 16 + lm];
            f32x4 cb; cb[0] = bi; cb[1] = bi; cb[2] = bi; cb[3] = bi;
            xm[0][f] = __builtin_amdgcn_mfma_f32_16x16x16f16(p0, wi, cb, 0, 0, 0);
            xm[1][f] = __builtin_amdgcn_mfma_f32_16x16x16f16(p1, wi, cb, 0, 0, 0);
        }
        // skip accumulator starts at sum_l skip_b (replaces per-layer adds)
#pragma unroll
        for (int f3 = 0; f3 < 2; ++f3) {
            f32x4 s = zero4;
#pragma unroll
            for (int l = 0; l < 4; ++l) {
                const float4 q = *(const float4*)&skip_b[l * 32 + f3 * 16 + kb * 4];
                s[0] += q.x; s[1] += q.y; s[2] += q.z; s[3] += q.w;
            }
            skT[f3][0] = s; skT[f3][1] = s;
        }
    }

#pragma unroll 1
    for (int l = 0; l < 4; ++l) {
        const bool pv = (t >= (1 << l));          // wave-uniform
        const float* B2 = BIAS + (l * 2 + (pv ? 1 : 0)) * 64;
        const int buf = l & 1;
        _Float16* xsb = (_Float16*)&xsT[ts][buf][0];

        // ---- publish xres (normal D -> chan-major LDS, per-ts buffer) ----
#pragma unroll
        for (int mt = 0; mt < 2; ++mt)
#pragma unroll
            for (int f = 0; f < 2; ++f)
                *(half4*)&xsb[(f * 16 + lm) * 136 + R + mt * 16 + kb * 4] = pack4(xm[mt][f]);

        // ---- prefetch (latency drains at the barrier) ----
        half8 Afr[2][4];
#pragma unroll
        for (int mt = 0; mt < 2; ++mt)
#pragma unroll
            for (int kt = 0; kt < 4; ++kt)
                Afr[mt][kt] = AFv[((ws * 2 + mt) * 4 + kt) * 64 + lane];
        const f32x4 cT0 = *(const f32x4*)&B2[0 * 16 + kb * 4];
        const f32x4 cT1 = *(const f32x4*)&B2[1 * 16 + kb * 4];
        const f32x4 cS0 = *(const f32x4*)&B2[32 + 0 * 16 + kb * 4];
        const f32x4 cS1 = *(const f32x4*)&B2[32 + 1 * 16 + kb * 4];

        __syncthreads();   // covers Pld staging (l=0) + both groups' publish

        // ---- conv MFMAs: K=32 = [prev-slab 16ch ; cur-slab 16ch] ----
        const int pslab = ts + ((0x0245 >> (l << 2)) & 15);   // l: 5,4,2,0 (+ts)
        const int cslab = 6 + ts;
        const int poff = (kb < 2) ? pslab * 16 + kb * 8 : cslab * 16 + (kb - 2) * 8;
        half8 pf0 = *(const half8*)&Pld[(R + lm) * 136 + poff];
        half8 pf1 = *(const half8*)&Pld[(R + 16 + lm) * 136 + poff];
        f32x4 dt[2][2], ds[2][2];                 // [ct][mt]
#pragma unroll
        for (int ct = 0; ct < 2; ++ct) {
            half8 wt = W32v[((l * 2 + 0) * 2 + ct) * 64 + lane];
            half8 ws8 = W32v[((l * 2 + 1) * 2 + ct) * 64 + lane];
            const f32x4 cT = ct ? cT1 : cT0;
            const f32x4 cS = ct ? cS1 : cS0;
            dt[ct][0] = __builtin_amdgcn_mfma_f32_16x16x32_f16(wt, pf0, cT, 0, 0, 0);
            dt[ct][1] = __builtin_amdgcn_mfma_f32_16x16x32_f16(wt, pf1, cT, 0, 0, 0);
            ds[ct][0] = __builtin_amdgcn_mfma_f32_16x16x32_f16(ws8, pf0, cS, 0, 0, 0);
            ds[ct][1] = __builtin_amdgcn_mfma_f32_16x16x32_f16(ws8, pf1, cS, 0, 0, 0);
        }

        // ---- A-mix: AxT[c][i] — A = xres^T frags (LDS), B = adjacency frags ----
        f32x4 AxT[2][2];                          // [f][mt]
#pragma unroll
        for (int f = 0; f < 2; ++f) {
            half8 xa[4];
#pragma unroll
            for (int kt = 0; kt < 4; ++kt)
                xa[kt] = *(const half8*)&xsb[(f * 16 + lm) * 136 + kt * 32 + kb * 8];
#pragma unroll
            for (int mt = 0; mt < 2; ++mt) {
                f32x4 acc = zero4;
#pragma unroll
                for (int kt = 0; kt < 4; ++kt)
                    acc = __builtin_amdgcn_mfma_f32_16x16x32_f16(xa[kt], Afr[mt][kt], acc, 0, 0, 0);
                AxT[f][mt] = acc;
            }
        }

        // ---- ts_act (exp chain overlaps A-mix MFMAs above) ----
        f32x4 tcv[2][2];                          // [ct][mt]
#pragma unroll
        for (int ct = 0; ct < 2; ++ct)
#pragma unroll
            for (int mt = 0; mt < 2; ++mt)
#pragma unroll
                for (int r = 0; r < 4; ++r)
                    tcv[ct][mt][r] = ts_act(dt[ct][mt][r], ds[ct][mt][r]);

        // ---- gcn_T: gcn_b rides C; add tcv after ----
        half4 axh[2][2];
#pragma unroll
        for (int f = 0; f < 2; ++f)
#pragma unroll
            for (int mt = 0; mt < 2; ++mt) axh[f][mt] = pack4(AxT[f][mt]);
        half4 hh[2][2];                           // h_T packed [g][mt]
#pragma unroll
        for (int gg = 0; gg < 2; ++gg) {
            half4 gw0 = W16v[((l * 3 + 0) * 4 + 0 + gg) * 64 + lane];
            half4 gw1 = W16v[((l * 3 + 0) * 4 + 2 + gg) * 64 + lane];
            const f32x4 gq = *(const f32x4*)&gcn_b[l * 32 + gg * 16 + kb * 4];
#pragma unroll
            for (int mt = 0; mt < 2; ++mt) {
                f32x4 acc = __builtin_amdgcn_mfma_f32_16x16x16f16(gw0, axh[0][mt], gq, 0, 0, 0);
                acc = __builtin_amdgcn_mfma_f32_16x16x16f16(gw1, axh[1][mt], acc, 0, 0, 0);
#pragma unroll
                for (int r = 0; r < 4; ++r) acc[r] += tcv[gg][mt][r];
                hh[gg][mt] = pack4(acc);
            }
        }

        // ---- res (normal) & skip_T (bias pre-folded into skT init) ----
#pragma unroll
        for (int mt = 0; mt < 2; ++mt)
#pragma unroll
            for (int f3 = 0; f3 < 2; ++f3) {
                half4 rw0 = W16v[((l * 3 + 1) * 4 + 0 + f3) * 64 + lane];
                half4 rw1 = W16v[((l * 3 + 1) * 4 + 2 + f3) * 64 + lane];
                f32x4 acc = __builtin_amdgcn_mfma_f32_16x16x16f16(hh[0][mt], rw0, xm[mt][f3], 0, 0, 0);
                xm[mt][f3] = __builtin_amdgcn_mfma_f32_16x16x16f16(hh[1][mt], rw1, acc, 0, 0, 0);
                float rb = res_b[l * 32 + f3 * 16 + lm];
#pragma unroll
                for (int r = 0; r < 4; ++r) xm[mt][f3][r] += rb;

                half4 sw0 = W16v[((l * 3 + 2) * 4 + 0 + f3) * 64 + lane];
                half4 sw1 = W16v[((l * 3 + 2) * 4 + 2 + f3) * 64 + lane];
                f32x4 acs = __builtin_amdgcn_mfma_f32_16x16x16f16(sw0, hh[0][mt], skT[f3][mt], 0, 0, 0);
                skT[f3][mt] = __builtin_amdgcn_mfma_f32_16x16x16f16(sw1, hh[1][mt], acs, 0, 0, 0);
            }
    }

    // ---- output head (biases ride C operands) ----
    half4 rs[2][2];
#pragma unroll
    for (int gg = 0; gg < 2; ++gg)
#pragma unroll
        for (int mt = 0; mt < 2; ++mt) {
            f32x4 v;
#pragma unroll
            for (int r = 0; r < 4; ++r) v[r] = fmaxf(skT[gg][mt][r], 0.f);
            rs[gg][mt] = pack4(v);
        }
    half4 h1h[2][2];
#pragma unroll
    for (int g4 = 0; g4 < 2; ++g4) {
        half4 w10 = W16v[(48 + 0 + g4) * 64 + lane];
        half4 w11 = W16v[(48 + 2 + g4) * 64 + lane];
        const f32x4 bq = *(const f32x4*)&b1[g4 * 16 + kb * 4];
#pragma unroll
        for (int mt = 0; mt < 2; ++mt) {
            f32x4 acc = __builtin_amdgcn_mfma_f32_16x16x16f16(w10, rs[0][mt], bq, 0, 0, 0);
            acc = __builtin_amdgcn_mfma_f32_16x16x16f16(w11, rs[1][mt], acc, 0, 0, 0);
            f32x4 v;
#pragma unroll
            for (int r = 0; r < 4; ++r) v[r] = fmaxf(acc[r], 0.f);
            h1h[g4][mt] = pack4(v);
        }
    }
    {
        half4 w20 = W16v[(52 + 0) * 64 + lane];
        half4 w21 = W16v[(52 + 2) * 64 + lane];
        const f32x4 b2q = *(const f32x4*)&b2[kb * 4];
        const size_t obase = (size_t)(b * 512 + t) * 128;
#pragma unroll
        for (int mt = 0; mt < 2; ++mt) {
            f32x4 acc = __builtin_amdgcn_mfma_f32_16x16x16f16(w20, h1h[0][mt], b2q, 0, 0, 0);
            acc = __builtin_amdgcn_mfma_f32_16x16x16f16(w21, h1h[1][mt], acc, 0, 0, 0);
            float4 o = make_float4(acc[0], acc[1], acc[2], acc[3]);
            *(float4*)&out[(obase + R + mt * 16 + lm) * 16 + kb * 4] = o;
        }
    }
}

// ---------------------------------------------------------------------------
extern "C" void kernel_launch(void* const* d_in, const int* in_sizes, int n_in,
                              void* d_out, int out_size, void* d_ws, size_t ws_size,
                              hipStream_t stream)
{
    const float* X      = (const float*)d_in[0];
    const float* A      = (const float*)d_in[1];
    const float* in_w   = (const float*)d_in[2];
    const float* in_b   = (const float*)d_in[3];
    const float* ct_w   = (const float*)d_in[4];
    const float* ct_b   = (const float*)d_in[5];
    const float* cs_w   = (const float*)d_in[6];
    const float* cs_b   = (const float*)d_in[7];
    const float* gcn_w  = (const float*)d_in[8];
    const float* gcn_b  = (const float*)d_in[9];
    const float* res_w  = (const float*)d_in[10];
    const float* res_b  = (const float*)d_in[11];
    const float* skip_w = (const float*)d_in[12];
    const float* skip_b = (const float*)d_in[13];
    const float* out1_w = (const float*)d_in[14];
    const float* out1_b = (const float*)d_in[15];
    const float* out2_w = (const float*)d_in[16];
    const float* out2_b = (const float*)d_in[17];

    _Float16* FR   = (_Float16*)d_ws;                 // 39936 f16 = 79872 B
    float*    BIAS = (float*)((char*)d_ws + 79872);   // 512 f32

    k_prep<<<158, 256, 0, stream>>>(A, in_w, in_b, ct_w, ct_b, cs_w, cs_b,
                                    gcn_w, res_w, skip_w, out1_w, out2_w,
                                    FR, BIAS);

    k_fused<<<8 * (T_ / 2), 512, 0, stream>>>(X, FR, BIAS, in_b,
                                              gcn_b, res_b, skip_b,
                                              out1_b, out2_b, (float*)d_out);
}

// Round 5
// 211.167 us; speedup vs baseline: 1.2299x; 1.2299x over previous
//
#include <hip/hip_runtime.h>
#include <math.h>

#define T_ 512

typedef _Float16 half8 __attribute__((ext_vector_type(8)));
typedef _Float16 half4 __attribute__((ext_vector_type(4)));
typedef float f32x4 __attribute__((ext_vector_type(4)));

// tanh(a)*sigmoid(b) = ((e^2a - 1) * e^b) / ((e^2a + 1) * (e^b + 1))
// single raw v_rcp instead of two full-precision divides.
__device__ __forceinline__ float ts_act(float a, float b) {
    float e2a = __expf(a + a);
    float eb  = __expf(b);
    float num = (e2a - 1.0f) * eb;
    float den = (e2a + 1.0f) * (eb + 1.0f);
    return num * __builtin_amdgcn_rcpf(den);
}

__device__ __forceinline__ half4 pack4(f32x4 v) {
    half4 h;
    h[0] = (_Float16)v[0]; h[1] = (_Float16)v[1];
    h[2] = (_Float16)v[2]; h[3] = (_Float16)v[3];
    return h;
}

// ---------------------------------------------------------------------------
// Prep fragment buffers in d_ws.
//  AF  [16384 f16] : adjacency, frag((it*4+kt))[lane][j] = A[it*16+(L&15)][kt*32+(L>>4)*8+j]
//  W32 [ 8192 f16] : K=32 folded conv mats (l*2+branch), 0..7
//                    frag idx (mat*2+ct)*64+L, slot j: W[k=(L>>4)*8+j][ct*16+(L&15)]
//  W16 [15360 f16] : K=16 mats: l*3+{0:gw,1:rw,2:sw} (0..11), 12:w1, 13:w2(pad), 14:winit16
//                    frag idx (mat*4+ks*2+ct)*64+L, slot i: W[ks*16+(L>>4)*4+i][ct*16+(L&15)]
//  BIAS[512 f32]   : pv-resolved conv biases: [(l*2+pv)*2+br]*32+n
// total idx = 16384+8192+15360+512 = 40448 = 158*256 (bytes: 79872 + 2048 = 81920)
// ---------------------------------------------------------------------------
__global__ __launch_bounds__(256) void k_prep(
    const float* __restrict__ A,     const float* __restrict__ in_w,
    const float* __restrict__ in_b,
    const float* __restrict__ ct_w,  const float* __restrict__ ct_b,
    const float* __restrict__ cs_w,  const float* __restrict__ cs_b,
    const float* __restrict__ gcn_w, const float* __restrict__ res_w,
    const float* __restrict__ skip_w,
    const float* __restrict__ out1_w,const float* __restrict__ out2_w,
    _Float16* __restrict__ FR, float* __restrict__ BIAS)
{
    int idx = blockIdx.x * 256 + threadIdx.x;
    if (idx < 16384) {
        int j = idx & 7, L = (idx >> 3) & 63, tile = idx >> 9;
        int it = tile >> 2, kt = tile & 3;
        FR[idx] = (_Float16)A[(it * 16 + (L & 15)) * 128 + kt * 32 + (L >> 4) * 8 + j];
    } else if (idx < 24576) {
        int e = idx - 16384;
        int j = e & 7, L = (e >> 3) & 63, ct = (e >> 9) & 1, mat = e >> 10;   // 0..7
        int k = (L >> 4) * 8 + j, col = ct * 16 + (L & 15);
        int l = mat >> 1, br = mat & 1;
        const float* tw = (br ? cs_w : ct_w) + l * 2048;
        int bro = br * 32;
        float v = 0.f;
        if (k < 16) { for (int c = 0; c < 32; ++c) v += in_w[k*96 + bro + c] * tw[c*32 + col]; }
        else        { for (int c = 0; c < 32; ++c) v += in_w[(k-16)*96 + bro + c] * tw[1024 + c*32 + col]; }
        FR[idx] = (_Float16)v;
    } else if (idx < 39936) {
        int e = idx - 24576;
        int i = e & 3, L = (e >> 2) & 63, ct = (e >> 8) & 1, ks = (e >> 9) & 1, mat = e >> 10; // 0..14
        int k = ks * 16 + (L >> 4) * 4 + i, col = ct * 16 + (L & 15);
        float v;
        if (mat < 12) {
            int l = mat / 3, r = mat - l * 3;
            const float* W = (r == 0) ? gcn_w : (r == 1) ? res_w : skip_w;
            v = W[l * 1024 + k * 32 + col];
        } else if (mat == 12) v = out1_w[k * 32 + col];
        else if (mat == 13)   v = (ct == 0) ? out2_w[k * 16 + (L & 15)] : 0.f;
        else                  v = (ks == 0) ? in_w[k * 96 + 64 + col] : 0.f;   // winit K=16
        FR[idx] = (_Float16)v;
    } else if (idx < 40448) {
        // pv-resolved conv biases: e = l*128 + pvi*64 + br*32 + n
        int e = idx - 39936;
        int n = e & 31, br = (e >> 5) & 1, pvi = (e >> 6) & 1, l = e >> 7;
        const float* W  = br ? cs_w : ct_w;
        const float* bb = br ? cs_b : ct_b;
        int ibo = br * 32;
        float v = bb[l * 32 + n];
        for (int c = 0; c < 32; ++c) v += in_b[ibo + c] * W[l*2048 + 1024 + c*32 + n]; // cur tap
        if (pvi)
            for (int c = 0; c < 32; ++c) v += in_b[ibo + c] * W[l*2048 + c*32 + n];    // prev tap
        BIAS[e] = v;
    }
}

// ---------------------------------------------------------------------------
// Fused net, timestep-PAIRED: one block per (b, t0=2*tp), 512 threads.
// Waves 0-3 compute time t0 (node tiles 0-3); waves 4-7 compute t0+1.
// The pair shares one Pld with the 8-slab union {t0-8,t0-7,t0-4,t0-3,
// t0-2,t0-1,t0,t0+1}: prev-slab(ts,l) = ts + {5,4,2,0}[l], cur = 6+ts.
// launch_bounds(512,3): cap ~170 VGPR — the proven no-spill regime
// (caps of exactly 128 flipped the allocator into 64-VGPR+spill in R1/R4).
// All slab offsets compile-time-indexed (runtime-indexed local array was
// lowering to scratch in R4).
// ---------------------------------------------------------------------------
__global__ __launch_bounds__(512, 3) void k_fused(
    const float* __restrict__ X,
    const _Float16* __restrict__ FR,
    const float* __restrict__ BIAS,
    const float* __restrict__ in_b,
    const float* __restrict__ gcn_b,
    const float* __restrict__ res_b,
    const float* __restrict__ skip_b,
    const float* __restrict__ b1,
    const float* __restrict__ b2,
    float* __restrict__ out)
{
    __shared__ _Float16 Pld[128 * 136];        // [node][slab0..7 (16 each)|pad8]
    __shared__ _Float16 xsT[2][2][32 * 136];   // [ts][pingpong][chan][node+pad8]

    const int bx = blockIdx.x;
    const int btp = ((bx & 7) << 8) | (bx >> 3);    // XCD j <- batch j
    const int b = btp >> 8, t0 = (btp & 255) * 2;
    const int tid = threadIdx.x, lane = tid & 63;
    const int g = tid >> 6, ts = g >> 2, ws = g & 3;
    const int t = t0 + ts;                          // this wave's timestep
    const int lm = lane & 15, kb = lane >> 4;
    const int R = ws * 32;
    const int row = lane >> 1, ch = lane & 1;

    const half8* AFv  = (const half8*)FR;
    const half8* W32v = (const half8*)(FR + 16384);
    const half4* W16v = (const half4*)(FR + 24576);
    const f32x4 zero4 = {0.f, 0.f, 0.f, 0.f};

    // ---- stage this group's 4 slabs of the 8-slab union ----
    // slab s holds time t0 + toff[s], toff = {-8,-7,-4,-3,-2,-1,0,+1}
    // ts=0 waves stage slabs 0..3 (toff -8,-7,-4,-3); ts=1 stage 4..7
    // (toff -2,-1,0,+1). sl is compile-time; ts select is a cndmask.
    {
        const size_t nrow = (size_t)(b * 128 + R + row) * T_;
#pragma unroll
        for (int sl = 0; sl < 4; ++sl) {
            const int offA[4] = {-8, -7, -4, -3};   // compile-time indexed
            const int offB[4] = {-2, -1,  0,  1};
            const int tt = t0 + (ts ? offB[sl] : offA[sl]);
            const int slab = ts * 4 + sl;
            half8 hv = {0,0,0,0,0,0,0,0};
            if (tt >= 0) {
                const float4* xp = (const float4*)(X + (nrow + tt) * 16 + ch * 8);
                float4 u0 = xp[0], u1 = xp[1];
                hv[0]=(_Float16)u0.x; hv[1]=(_Float16)u0.y; hv[2]=(_Float16)u0.z; hv[3]=(_Float16)u0.w;
                hv[4]=(_Float16)u1.x; hv[5]=(_Float16)u1.y; hv[6]=(_Float16)u1.z; hv[7]=(_Float16)u1.w;
            }
            *(half8*)&Pld[(R + row) * 136 + slab * 16 + ch * 8] = hv;
        }
    }

    // ---- xres init: K=16 MFMA straight from registers (true coords) ----
    f32x4 xm[2][2], skT[2][2];
    {
        const size_t base = (size_t)(b * 512 + t) * 128;
        const float4 x0 = *(const float4*)(X + (base + R + lm) * 16 + kb * 4);
        const float4 x1 = *(const float4*)(X + (base + R + 16 + lm) * 16 + kb * 4);
        half4 p0, p1;
        p0[0]=(_Float16)x0.x; p0[1]=(_Float16)x0.y; p0[2]=(_Float16)x0.z; p0[3]=(_Float16)x0.w;
        p1[0]=(_Float16)x1.x; p1[1]=(_Float16)x1.y; p1[2]=(_Float16)x1.z; p1[3]=(_Float16)x1.w;
#pragma unroll
        for (int f = 0; f < 2; ++f) {
            half4 wi = W16v[(56 + f) * 64 + lane];          // winit mat 14, ks=0
            float bi = in_b[64 + f * 16 + lm];
            f32x4 cb; cb[0] = bi; cb[1] = bi; cb[2] = bi; cb[3] = bi;
            xm[0][f] = __builtin_amdgcn_mfma_f32_16x16x16f16(p0, wi, cb, 0, 0, 0);
            xm[1][f] = __builtin_amdgcn_mfma_f32_16x16x16f16(p1, wi, cb, 0, 0, 0);
        }
        // skip accumulator starts at sum_l skip_b (replaces per-layer adds)
#pragma unroll
        for (int f3 = 0; f3 < 2; ++f3) {
            f32x4 s = zero4;
#pragma unroll
            for (int l = 0; l < 4; ++l) {
                const float4 q = *(const float4*)&skip_b[l * 32 + f3 * 16 + kb * 4];
                s[0] += q.x; s[1] += q.y; s[2] += q.z; s[3] += q.w;
            }
            skT[f3][0] = s; skT[f3][1] = s;
        }
    }

#pragma unroll 1
    for (int l = 0; l < 4; ++l) {
        const bool pv = (t >= (1 << l));          // wave-uniform
        const float* B2 = BIAS + (l * 2 + (pv ? 1 : 0)) * 64;
        const int buf = l & 1;
        _Float16* xsb = (_Float16*)&xsT[ts][buf][0];

        // ---- publish xres (normal D -> chan-major LDS, per-ts buffer) ----
#pragma unroll
        for (int mt = 0; mt < 2; ++mt)
#pragma unroll
            for (int f = 0; f < 2; ++f)
                *(half4*)&xsb[(f * 16 + lm) * 136 + R + mt * 16 + kb * 4] = pack4(xm[mt][f]);

        // ---- prefetch (latency drains at the barrier) ----
        half8 Afr[2][4];
#pragma unroll
        for (int mt = 0; mt < 2; ++mt)
#pragma unroll
            for (int kt = 0; kt < 4; ++kt)
                Afr[mt][kt] = AFv[((ws * 2 + mt) * 4 + kt) * 64 + lane];
        const f32x4 cT0 = *(const f32x4*)&B2[0 * 16 + kb * 4];
        const f32x4 cT1 = *(const f32x4*)&B2[1 * 16 + kb * 4];
        const f32x4 cS0 = *(const f32x4*)&B2[32 + 0 * 16 + kb * 4];
        const f32x4 cS1 = *(const f32x4*)&B2[32 + 1 * 16 + kb * 4];

        __syncthreads();   // covers Pld staging (l=0) + both groups' publish

        // ---- conv MFMAs: K=32 = [prev-slab 16ch ; cur-slab 16ch] ----
        const int pslab = ts + ((0x0245 >> (l << 2)) & 15);   // l: 5,4,2,0 (+ts)
        const int cslab = 6 + ts;
        const int poff = (kb < 2) ? pslab * 16 + kb * 8 : cslab * 16 + (kb - 2) * 8;
        half8 pf0 = *(const half8*)&Pld[(R + lm) * 136 + poff];
        half8 pf1 = *(const half8*)&Pld[(R + 16 + lm) * 136 + poff];
        f32x4 dt[2][2], ds[2][2];                 // [ct][mt]
#pragma unroll
        for (int ct = 0; ct < 2; ++ct) {
            half8 wt = W32v[((l * 2 + 0) * 2 + ct) * 64 + lane];
            half8 ws8 = W32v[((l * 2 + 1) * 2 + ct) * 64 + lane];
            const f32x4 cT = ct ? cT1 : cT0;
            const f32x4 cS = ct ? cS1 : cS0;
            dt[ct][0] = __builtin_amdgcn_mfma_f32_16x16x32_f16(wt, pf0, cT, 0, 0, 0);
            dt[ct][1] = __builtin_amdgcn_mfma_f32_16x16x32_f16(wt, pf1, cT, 0, 0, 0);
            ds[ct][0] = __builtin_amdgcn_mfma_f32_16x16x32_f16(ws8, pf0, cS, 0, 0, 0);
            ds[ct][1] = __builtin_amdgcn_mfma_f32_16x16x32_f16(ws8, pf1, cS, 0, 0, 0);
        }

        // ---- A-mix: AxT[c][i] — A = xres^T frags (LDS), B = adjacency frags ----
        f32x4 AxT[2][2];                          // [f][mt]
#pragma unroll
        for (int f = 0; f < 2; ++f) {
            half8 xa[4];
#pragma unroll
            for (int kt = 0; kt < 4; ++kt)
                xa[kt] = *(const half8*)&xsb[(f * 16 + lm) * 136 + kt * 32 + kb * 8];
#pragma unroll
            for (int mt = 0; mt < 2; ++mt) {
                f32x4 acc = zero4;
#pragma unroll
                for (int kt = 0; kt < 4; ++kt)
                    acc = __builtin_amdgcn_mfma_f32_16x16x32_f16(xa[kt], Afr[mt][kt], acc, 0, 0, 0);
                AxT[f][mt] = acc;
            }
        }

        // ---- ts_act (exp chain overlaps A-mix MFMAs above) ----
        f32x4 tcv[2][2];                          // [ct][mt]
#pragma unroll
        for (int ct = 0; ct < 2; ++ct)
#pragma unroll
            for (int mt = 0; mt < 2; ++mt)
#pragma unroll
                for (int r = 0; r < 4; ++r)
                    tcv[ct][mt][r] = ts_act(dt[ct][mt][r], ds[ct][mt][r]);

        // ---- gcn_T: gcn_b rides C; add tcv after ----
        half4 axh[2][2];
#pragma unroll
        for (int f = 0; f < 2; ++f)
#pragma unroll
            for (int mt = 0; mt < 2; ++mt) axh[f][mt] = pack4(AxT[f][mt]);
        half4 hh[2][2];                           // h_T packed [g][mt]
#pragma unroll
        for (int gg = 0; gg < 2; ++gg) {
            half4 gw0 = W16v[((l * 3 + 0) * 4 + 0 + gg) * 64 + lane];
            half4 gw1 = W16v[((l * 3 + 0) * 4 + 2 + gg) * 64 + lane];
            const f32x4 gq = *(const f32x4*)&gcn_b[l * 32 + gg * 16 + kb * 4];
#pragma unroll
            for (int mt = 0; mt < 2; ++mt) {
                f32x4 acc = __builtin_amdgcn_mfma_f32_16x16x16f16(gw0, axh[0][mt], gq, 0, 0, 0);
                acc = __builtin_amdgcn_mfma_f32_16x16x16f16(gw1, axh[1][mt], acc, 0, 0, 0);
#pragma unroll
                for (int r = 0; r < 4; ++r) acc[r] += tcv[gg][mt][r];
                hh[gg][mt] = pack4(acc);
            }
        }

        // ---- res (normal) & skip_T (bias pre-folded into skT init) ----
#pragma unroll
        for (int mt = 0; mt < 2; ++mt)
#pragma unroll
            for (int f3 = 0; f3 < 2; ++f3) {
                half4 rw0 = W16v[((l * 3 + 1) * 4 + 0 + f3) * 64 + lane];
                half4 rw1 = W16v[((l * 3 + 1) * 4 + 2 + f3) * 64 + lane];
                f32x4 acc = __builtin_amdgcn_mfma_f32_16x16x16f16(hh[0][mt], rw0, xm[mt][f3], 0, 0, 0);
                xm[mt][f3] = __builtin_amdgcn_mfma_f32_16x16x16f16(hh[1][mt], rw1, acc, 0, 0, 0);
                float rb = res_b[l * 32 + f3 * 16 + lm];
#pragma unroll
                for (int r = 0; r < 4; ++r) xm[mt][f3][r] += rb;

                half4 sw0 = W16v[((l * 3 + 2) * 4 + 0 + f3) * 64 + lane];
                half4 sw1 = W16v[((l * 3 + 2) * 4 + 2 + f3) * 64 + lane];
                f32x4 acs = __builtin_amdgcn_mfma_f32_16x16x16f16(sw0, hh[0][mt], skT[f3][mt], 0, 0, 0);
                skT[f3][mt] = __builtin_amdgcn_mfma_f32_16x16x16f16(sw1, hh[1][mt], acs, 0, 0, 0);
            }
    }

    // ---- output head (biases ride C operands) ----
    half4 rs[2][2];
#pragma unroll
    for (int gg = 0; gg < 2; ++gg)
#pragma unroll
        for (int mt = 0; mt < 2; ++mt) {
            f32x4 v;
#pragma unroll
            for (int r = 0; r < 4; ++r) v[r] = fmaxf(skT[gg][mt][r], 0.f);
            rs[gg][mt] = pack4(v);
        }
    half4 h1h[2][2];
#pragma unroll
    for (int g4 = 0; g4 < 2; ++g4) {
        half4 w10 = W16v[(48 + 0 + g4) * 64 + lane];
        half4 w11 = W16v[(48 + 2 + g4) * 64 + lane];
        const f32x4 bq = *(const f32x4*)&b1[g4 * 16 + kb * 4];
#pragma unroll
        for (int mt = 0; mt < 2; ++mt) {
            f32x4 acc = __builtin_amdgcn_mfma_f32_16x16x16f16(w10, rs[0][mt], bq, 0, 0, 0);
            acc = __builtin_amdgcn_mfma_f32_16x16x16f16(w11, rs[1][mt], acc, 0, 0, 0);
            f32x4 v;
#pragma unroll
            for (int r = 0; r < 4; ++r) v[r] = fmaxf(acc[r], 0.f);
            h1h[g4][mt] = pack4(v);
        }
    }
    {
        half4 w20 = W16v[(52 + 0) * 64 + lane];
        half4 w21 = W16v[(52 + 2) * 64 + lane];
        const f32x4 b2q = *(const f32x4*)&b2[kb * 4];
        const size_t obase = (size_t)(b * 512 + t) * 128;
#pragma unroll
        for (int mt = 0; mt < 2; ++mt) {
            f32x4 acc = __builtin_amdgcn_mfma_f32_16x16x16f16(w20, h1h[0][mt], b2q, 0, 0, 0);
            acc = __builtin_amdgcn_mfma_f32_16x16x16f16(w21, h1h[1][mt], acc, 0, 0, 0);
            float4 o = make_float4(acc[0], acc[1], acc[2], acc[3]);
            *(float4*)&out[(obase + R + mt * 16 + lm) * 16 + kb * 4] = o;
        }
    }
}

// ---------------------------------------------------------------------------
extern "C" void kernel_launch(void* const* d_in, const int* in_sizes, int n_in,
                              void* d_out, int out_size, void* d_ws, size_t ws_size,
                              hipStream_t stream)
{
    const float* X      = (const float*)d_in[0];
    const float* A      = (const float*)d_in[1];
    const float* in_w   = (const float*)d_in[2];
    const float* in_b   = (const float*)d_in[3];
    const float* ct_w   = (const float*)d_in[4];
    const float* ct_b   = (const float*)d_in[5];
    const float* cs_w   = (const float*)d_in[6];
    const float* cs_b   = (const float*)d_in[7];
    const float* gcn_w  = (const float*)d_in[8];
    const float* gcn_b  = (const float*)d_in[9];
    const float* res_w  = (const float*)d_in[10];
    const float* res_b  = (const float*)d_in[11];
    const float* skip_w = (const float*)d_in[12];
    const float* skip_b = (const float*)d_in[13];
    const float* out1_w = (const float*)d_in[14];
    const float* out1_b = (const float*)d_in[15];
    const float* out2_w = (const float*)d_in[16];
    const float* out2_b = (const float*)d_in[17];

    _Float16* FR   = (_Float16*)d_ws;                 // 39936 f16 = 79872 B
    float*    BIAS = (float*)((char*)d_ws + 79872);   // 512 f32

    k_prep<<<158, 256, 0, stream>>>(A, in_w, in_b, ct_w, ct_b, cs_w, cs_b,
                                    gcn_w, res_w, skip_w, out1_w, out2_w,
                                    FR, BIAS);

    k_fused<<<8 * (T_ / 2), 512, 0, stream>>>(X, FR, BIAS, in_b,
                                              gcn_b, res_b, skip_b,
                                              out1_b, out2_b, (float*)d_out);
}

// Round 7
// 209.168 us; speedup vs baseline: 1.2417x; 1.0096x over previous
//
#include <hip/hip_runtime.h>
#include <math.h>

#define T_ 512

typedef _Float16 half8 __attribute__((ext_vector_type(8)));
typedef _Float16 half4 __attribute__((ext_vector_type(4)));
typedef _Float16 half2 __attribute__((ext_vector_type(2)));
typedef __fp16  pk2   __attribute__((ext_vector_type(2)));   // cvt_pkrtz return type
typedef float f32x4 __attribute__((ext_vector_type(4)));

__device__ __forceinline__ half2 cvt2(float x, float y) {
    pk2 p = __builtin_amdgcn_cvt_pkrtz(x, y);
    return __builtin_bit_cast(half2, p);
}

// Folded gated activation. k_prep pre-scales the tanh-branch weights/biases by
// 2*log2(e) and the sigmoid-branch by log2(e), so:
//   tanh(a)*sigm(b) = (exp2(a')-1)*exp2(b') / ((exp2(a')+1)*(exp2(b')+1))
// 2 x v_exp + 7 VALU, single raw rcp, gcn bias rides the final fma.
__device__ __forceinline__ float ts_act2(float a, float b, float gb) {
    float e2a = __builtin_exp2f(a);
    float eb  = __builtin_exp2f(b);
    float num = (e2a - 1.0f) * eb;
    float den = (e2a + 1.0f) * (eb + 1.0f);
    return fmaf(num, __builtin_amdgcn_rcpf(den), gb);
}

__device__ __forceinline__ half4 pack4(f32x4 v) {
    half2 lo = cvt2(v[0], v[1]);
    half2 hi = cvt2(v[2], v[3]);
    half4 h; h[0] = lo[0]; h[1] = lo[1]; h[2] = hi[0]; h[3] = hi[1];
    return h;
}
__device__ __forceinline__ half4 pack4f(float4 v) {
    half2 lo = cvt2(v.x, v.y);
    half2 hi = cvt2(v.z, v.w);
    half4 h; h[0] = lo[0]; h[1] = lo[1]; h[2] = hi[0]; h[3] = hi[1];
    return h;
}
__device__ __forceinline__ half8 pack8(float4 u0, float4 u1) {
    half2 a = cvt2(u0.x, u0.y);
    half2 b = cvt2(u0.z, u0.w);
    half2 c = cvt2(u1.x, u1.y);
    half2 d = cvt2(u1.z, u1.w);
    half8 h;
    h[0]=a[0]; h[1]=a[1]; h[2]=b[0]; h[3]=b[1];
    h[4]=c[0]; h[5]=c[1]; h[6]=d[0]; h[7]=d[1];
    return h;
}

// ---------------------------------------------------------------------------
// Prep fragment buffers in d_ws.
//  AF  [16384 f16] : adjacency, frag((it*4+kt))[lane][j] = A[it*16+(L&15)][kt*32+(L>>4)*8+j]
//  W32 [ 8192 f16] : K=32 folded conv mats (l*2+branch), 0..7 — PRE-SCALED by
//                    2*log2e (branch 0 / tanh) or log2e (branch 1 / sigm)
//  W16 [15360 f16] : K=16 mats: l*3+{0:gw,1:rw,2:sw} (0..11), 12:w1, 13:w2(pad), 14:winit16
//  BIAS[512 f32]   : pv-resolved conv biases (same pre-scaling): [(l*2+pv)*2+br]*32+n
// ---------------------------------------------------------------------------
__global__ __launch_bounds__(256) void k_prep(
    const float* __restrict__ A,     const float* __restrict__ in_w,
    const float* __restrict__ in_b,
    const float* __restrict__ ct_w,  const float* __restrict__ ct_b,
    const float* __restrict__ cs_w,  const float* __restrict__ cs_b,
    const float* __restrict__ gcn_w, const float* __restrict__ res_w,
    const float* __restrict__ skip_w,
    const float* __restrict__ out1_w,const float* __restrict__ out2_w,
    _Float16* __restrict__ FR, float* __restrict__ BIAS)
{
    int idx = blockIdx.x * 256 + threadIdx.x;
    if (idx < 16384) {
        int j = idx & 7, L = (idx >> 3) & 63, tile = idx >> 9;
        int it = tile >> 2, kt = tile & 3;
        FR[idx] = (_Float16)A[(it * 16 + (L & 15)) * 128 + kt * 32 + (L >> 4) * 8 + j];
    } else if (idx < 24576) {
        int e = idx - 16384;
        int j = e & 7, L = (e >> 3) & 63, ct = (e >> 9) & 1, mat = e >> 10;   // 0..7
        int k = (L >> 4) * 8 + j, col = ct * 16 + (L & 15);
        int l = mat >> 1, br = mat & 1;
        const float* tw = (br ? cs_w : ct_w) + l * 2048;
        int bro = br * 32;
        float v = 0.f;
        if (k < 16) { for (int c = 0; c < 32; ++c) v += in_w[k*96 + bro + c] * tw[c*32 + col]; }
        else        { for (int c = 0; c < 32; ++c) v += in_w[(k-16)*96 + bro + c] * tw[1024 + c*32 + col]; }
        v *= (br ? 1.4426950408889634f : 2.8853900817779268f);   // exp2 folding
        FR[idx] = (_Float16)v;
    } else if (idx < 39936) {
        int e = idx - 24576;
        int i = e & 3, L = (e >> 2) & 63, ct = (e >> 8) & 1, ks = (e >> 9) & 1, mat = e >> 10; // 0..14
        int k = ks * 16 + (L >> 4) * 4 + i, col = ct * 16 + (L & 15);
        float v;
        if (mat < 12) {
            int l = mat / 3, r = mat - l * 3;
            const float* W = (r == 0) ? gcn_w : (r == 1) ? res_w : skip_w;
            v = W[l * 1024 + k * 32 + col];
        } else if (mat == 12) v = out1_w[k * 32 + col];
        else if (mat == 13)   v = (ct == 0) ? out2_w[k * 16 + (L & 15)] : 0.f;
        else                  v = (ks == 0) ? in_w[k * 96 + 64 + col] : 0.f;   // winit K=16
        FR[idx] = (_Float16)v;
    } else if (idx < 40448) {
        // pv-resolved conv biases: e = l*128 + pvi*64 + br*32 + n
        int e = idx - 39936;
        int n = e & 31, br = (e >> 5) & 1, pvi = (e >> 6) & 1, l = e >> 7;
        const float* W  = br ? cs_w : ct_w;
        const float* bb = br ? cs_b : ct_b;
        int ibo = br * 32;
        float v = bb[l * 32 + n];
        for (int c = 0; c < 32; ++c) v += in_b[ibo + c] * W[l*2048 + 1024 + c*32 + n]; // cur tap
        if (pvi)
            for (int c = 0; c < 32; ++c) v += in_b[ibo + c] * W[l*2048 + c*32 + n];    // prev tap
        BIAS[e] = v * (br ? 1.4426950408889634f : 2.8853900817779268f);    // exp2 folding
    }
}

// ---------------------------------------------------------------------------
// Fused net. One block per (b,t), 256 threads (R3 base — the 512-thread pair
// structure measured -18% in R5). All 5 conv slabs pre-staged; layer loop
// FULLY UNROLLED (l literal -> fragment offsets constant-fold); adjacency
// frags hoisted across layers under the (256,3) no-spill cap; packed
// cvt_pkrtz conversions; exp2-folded activation with gcn_b riding its fma.
// ---------------------------------------------------------------------------
__global__ __launch_bounds__(256, 3) void k_fused(
    const float* __restrict__ X,
    const _Float16* __restrict__ FR,
    const float* __restrict__ BIAS,
    const float* __restrict__ in_b,
    const float* __restrict__ gcn_b,
    const float* __restrict__ res_b,
    const float* __restrict__ skip_b,
    const float* __restrict__ b1,
    const float* __restrict__ b2,
    float* __restrict__ out)
{
    __shared__ _Float16 Pld[128 * 88];        // [node][p0|p1|p2|p3|cur|pad8], stride 88
    __shared__ _Float16 xsT[2][32 * 136];     // [chan][node(128)+pad8], ping-pong

    const int bx = blockIdx.x;
    const int btid = ((bx & 7) << 9) | (bx >> 3);   // XCD j <- batch j
    const int b = btid >> 9, t = btid & (T_ - 1);
    const int tid = threadIdx.x, lane = tid & 63, w = tid >> 6;
    const int lm = lane & 15, kb = lane >> 4;
    const int R = w * 32;
    const int row = lane >> 1, ch = lane & 1;

    const half8* AFv  = (const half8*)FR;
    const half8* W32v = (const half8*)(FR + 16384);
    const half4* W16v = (const half4*)(FR + 24576);
    const f32x4 zero4 = {0.f, 0.f, 0.f, 0.f};

    // ---- stage ALL conv slabs up-front (one load burst, max MLP) ----
    {
        const size_t nrow = (size_t)(b * 128 + R + row) * T_;
        const float4* xc = (const float4*)(X + (nrow + t) * 16 + ch * 8);
        float4 c0 = xc[0], c1 = xc[1];
        float4 p0[4], p1[4];
#pragma unroll
        for (int l = 0; l < 4; ++l) {
            const int d = 1 << l;
            if (t >= d) {
                const float4* xp = (const float4*)(X + (nrow + (t - d)) * 16 + ch * 8);
                p0[l] = xp[0]; p1[l] = xp[1];
            } else {
                p0[l] = make_float4(0.f, 0.f, 0.f, 0.f);
                p1[l] = make_float4(0.f, 0.f, 0.f, 0.f);
            }
        }
        *(half8*)&Pld[(R + row) * 88 + 64 + ch * 8] = pack8(c0, c1);
#pragma unroll
        for (int l = 0; l < 4; ++l)
            *(half8*)&Pld[(R + row) * 88 + l * 16 + ch * 8] = pack8(p0[l], p1[l]);
    }

    // ---- hoisted adjacency fragments (layer-invariant, 32 VGPRs) ----
    half8 Afr[2][4];
#pragma unroll
    for (int mt = 0; mt < 2; ++mt)
#pragma unroll
        for (int kt = 0; kt < 4; ++kt)
            Afr[mt][kt] = AFv[((w * 2 + mt) * 4 + kt) * 64 + lane];

    // ---- xres init: K=16 MFMA straight from registers (true coords) ----
    f32x4 xm[2][2], skT[2][2];
    {
        const float4 x0 = *(const float4*)(X + ((size_t)btid * 128 + R + lm) * 16 + kb * 4);
        const float4 x1 = *(const float4*)(X + ((size_t)btid * 128 + R + 16 + lm) * 16 + kb * 4);
        half4 p0 = pack4f(x0), p1 = pack4f(x1);
#pragma unroll
        for (int f = 0; f < 2; ++f) {
            half4 wi = W16v[(56 + f) * 64 + lane];          // winit mat 14, ks=0
            float bi = in_b[64 + f * 16 + lm];
            f32x4 cb; cb[0] = bi; cb[1] = bi; cb[2] = bi; cb[3] = bi;
            xm[0][f] = __builtin_amdgcn_mfma_f32_16x16x16f16(p0, wi, cb, 0, 0, 0);
            xm[1][f] = __builtin_amdgcn_mfma_f32_16x16x16f16(p1, wi, cb, 0, 0, 0);
        }
        // skip accumulator starts at sum_l skip_b (replaces per-layer adds)
#pragma unroll
        for (int f3 = 0; f3 < 2; ++f3) {
            f32x4 s = zero4;
#pragma unroll
            for (int l = 0; l < 4; ++l) {
                const float4 q = *(const float4*)&skip_b[l * 32 + f3 * 16 + kb * 4];
                s[0] += q.x; s[1] += q.y; s[2] += q.z; s[3] += q.w;
            }
            skT[f3][0] = s; skT[f3][1] = s;
        }
    }

    // per-lane conv fragment offset: kb<2 -> prev slab l (halves l*16+kb*8),
    // kb>=2 -> cur slab (halves 64+(kb-2)*8)
    const int fragoff = (kb < 2) ? kb * 8 : 64 + (kb - 2) * 8;
    const int lstep   = (kb < 2) ? 16 : 0;

#pragma unroll
    for (int l = 0; l < 4; ++l) {
        const bool pv = (t >= (1 << l));          // block-uniform
        const float* B2 = BIAS + (l * 2 + (pv ? 1 : 0)) * 64;
        const int buf = l & 1;

        // ---- publish xres (normal D -> chan-major LDS) ----
#pragma unroll
        for (int mt = 0; mt < 2; ++mt)
#pragma unroll
            for (int f = 0; f < 2; ++f)
                *(half4*)&xsT[buf][(f * 16 + lm) * 136 + R + mt * 16 + kb * 4] = pack4(xm[mt][f]);

        // ---- prefetch biases (latency drains at the barrier) ----
        const f32x4 cT0 = *(const f32x4*)&B2[0 * 16 + kb * 4];
        const f32x4 cT1 = *(const f32x4*)&B2[1 * 16 + kb * 4];
        const f32x4 cS0 = *(const f32x4*)&B2[32 + 0 * 16 + kb * 4];
        const f32x4 cS1 = *(const f32x4*)&B2[32 + 1 * 16 + kb * 4];
        const f32x4 gq0 = *(const f32x4*)&gcn_b[l * 32 + 0 * 16 + kb * 4];
        const f32x4 gq1 = *(const f32x4*)&gcn_b[l * 32 + 1 * 16 + kb * 4];

        __syncthreads();

        // ---- conv MFMAs (raw outputs kept; act deferred past A-mix) ----
        const int poff = fragoff + l * lstep;
        half8 pf0 = *(const half8*)&Pld[(R + lm) * 88 + poff];
        half8 pf1 = *(const half8*)&Pld[(R + 16 + lm) * 88 + poff];
        f32x4 dt[2][2], ds[2][2];                 // [ct][mt]
#pragma unroll
        for (int ct = 0; ct < 2; ++ct) {
            half8 wt = W32v[((l * 2 + 0) * 2 + ct) * 64 + lane];
            half8 ws = W32v[((l * 2 + 1) * 2 + ct) * 64 + lane];
            const f32x4 cT = ct ? cT1 : cT0;
            const f32x4 cS = ct ? cS1 : cS0;
            dt[ct][0] = __builtin_amdgcn_mfma_f32_16x16x32_f16(wt, pf0, cT, 0, 0, 0);
            dt[ct][1] = __builtin_amdgcn_mfma_f32_16x16x32_f16(wt, pf1, cT, 0, 0, 0);
            ds[ct][0] = __builtin_amdgcn_mfma_f32_16x16x32_f16(ws, pf0, cS, 0, 0, 0);
            ds[ct][1] = __builtin_amdgcn_mfma_f32_16x16x32_f16(ws, pf1, cS, 0, 0, 0);
        }

        // ---- A-mix: AxT[c][i] — A = xres^T frags (LDS), B = adjacency frags ----
        f32x4 AxT[2][2];                          // [f][mt]
#pragma unroll
        for (int f = 0; f < 2; ++f) {
            half8 xa[4];
#pragma unroll
            for (int kt = 0; kt < 4; ++kt)
                xa[kt] = *(const half8*)&xsT[buf][(f * 16 + lm) * 136 + kt * 32 + kb * 8];
#pragma unroll
            for (int mt = 0; mt < 2; ++mt) {
                f32x4 acc = zero4;
#pragma unroll
                for (int kt = 0; kt < 4; ++kt)
                    acc = __builtin_amdgcn_mfma_f32_16x16x32_f16(xa[kt], Afr[mt][kt], acc, 0, 0, 0);
                AxT[f][mt] = acc;
            }
        }

        // ---- act (exp chain overlaps A-mix MFMAs above); gcn_b rides fma ----
        f32x4 tcv[2][2];                          // [ct][mt], = act + gcn_b
#pragma unroll
        for (int ct = 0; ct < 2; ++ct) {
            const f32x4 gq = ct ? gq1 : gq0;
#pragma unroll
            for (int mt = 0; mt < 2; ++mt)
#pragma unroll
                for (int r = 0; r < 4; ++r)
                    tcv[ct][mt][r] = ts_act2(dt[ct][mt][r], ds[ct][mt][r], gq[r]);
        }

        // ---- gcn_T: C chain starts at tcv (act + gcn_b) ----
        half4 axh[2][2];
#pragma unroll
        for (int f = 0; f < 2; ++f)
#pragma unroll
            for (int mt = 0; mt < 2; ++mt) axh[f][mt] = pack4(AxT[f][mt]);
        half4 hh[2][2];                           // h_T packed [g][mt]
#pragma unroll
        for (int g = 0; g < 2; ++g) {
            half4 gw0 = W16v[((l * 3 + 0) * 4 + 0 + g) * 64 + lane];
            half4 gw1 = W16v[((l * 3 + 0) * 4 + 2 + g) * 64 + lane];
#pragma unroll
            for (int mt = 0; mt < 2; ++mt) {
                f32x4 acc = __builtin_amdgcn_mfma_f32_16x16x16f16(gw1, axh[1][mt], tcv[g][mt], 0, 0, 0);
                acc = __builtin_amdgcn_mfma_f32_16x16x16f16(gw0, axh[0][mt], acc, 0, 0, 0);
                hh[g][mt] = pack4(acc);
            }
        }

        // ---- res (normal) & skip_T (bias pre-folded into skT init) ----
#pragma unroll
        for (int mt = 0; mt < 2; ++mt)
#pragma unroll
            for (int f3 = 0; f3 < 2; ++f3) {
                half4 rw0 = W16v[((l * 3 + 1) * 4 + 0 + f3) * 64 + lane];
                half4 rw1 = W16v[((l * 3 + 1) * 4 + 2 + f3) * 64 + lane];
                f32x4 acc = __builtin_amdgcn_mfma_f32_16x16x16f16(hh[0][mt], rw0, xm[mt][f3], 0, 0, 0);
                xm[mt][f3] = __builtin_amdgcn_mfma_f32_16x16x16f16(hh[1][mt], rw1, acc, 0, 0, 0);
                float rb = res_b[l * 32 + f3 * 16 + lm];
#pragma unroll
                for (int r = 0; r < 4; ++r) xm[mt][f3][r] += rb;

                half4 sw0 = W16v[((l * 3 + 2) * 4 + 0 + f3) * 64 + lane];
                half4 sw1 = W16v[((l * 3 + 2) * 4 + 2 + f3) * 64 + lane];
                f32x4 acs = __builtin_amdgcn_mfma_f32_16x16x16f16(sw0, hh[0][mt], skT[f3][mt], 0, 0, 0);
                skT[f3][mt] = __builtin_amdgcn_mfma_f32_16x16x16f16(sw1, hh[1][mt], acs, 0, 0, 0);
            }
    }

    // ---- output head (biases ride C operands) ----
    half4 rs[2][2];
#pragma unroll
    for (int g = 0; g < 2; ++g)
#pragma unroll
        for (int mt = 0; mt < 2; ++mt) {
            f32x4 v;
#pragma unroll
            for (int r = 0; r < 4; ++r) v[r] = fmaxf(skT[g][mt][r], 0.f);
            rs[g][mt] = pack4(v);
        }
    half4 h1h[2][2];
#pragma unroll
    for (int g4 = 0; g4 < 2; ++g4) {
        half4 w10 = W16v[(48 + 0 + g4) * 64 + lane];
        half4 w11 = W16v[(48 + 2 + g4) * 64 + lane];
        const f32x4 bq = *(const f32x4*)&b1[g4 * 16 + kb * 4];
#pragma unroll
        for (int mt = 0; mt < 2; ++mt) {
            f32x4 acc = __builtin_amdgcn_mfma_f32_16x16x16f16(w10, rs[0][mt], bq, 0, 0, 0);
            acc = __builtin_amdgcn_mfma_f32_16x16x16f16(w11, rs[1][mt], acc, 0, 0, 0);
            f32x4 v;
#pragma unroll
            for (int r = 0; r < 4; ++r) v[r] = fmaxf(acc[r], 0.f);
            h1h[g4][mt] = pack4(v);
        }
    }
    {
        half4 w20 = W16v[(52 + 0) * 64 + lane];
        half4 w21 = W16v[(52 + 2) * 64 + lane];
        const f32x4 b2q = *(const f32x4*)&b2[kb * 4];
#pragma unroll
        for (int mt = 0; mt < 2; ++mt) {
            f32x4 acc = __builtin_amdgcn_mfma_f32_16x16x16f16(w20, h1h[0][mt], b2q, 0, 0, 0);
            acc = __builtin_amdgcn_mfma_f32_16x16x16f16(w21, h1h[1][mt], acc, 0, 0, 0);
            float4 o = make_float4(acc[0], acc[1], acc[2], acc[3]);
            *(float4*)&out[((size_t)btid * 128 + R + mt * 16 + lm) * 16 + kb * 4] = o;
        }
    }
}

// ---------------------------------------------------------------------------
extern "C" void kernel_launch(void* const* d_in, const int* in_sizes, int n_in,
                              void* d_out, int out_size, void* d_ws, size_t ws_size,
                              hipStream_t stream)
{
    const float* X      = (const float*)d_in[0];
    const float* A      = (const float*)d_in[1];
    const float* in_w   = (const float*)d_in[2];
    const float* in_b   = (const float*)d_in[3];
    const float* ct_w   = (const float*)d_in[4];
    const float* ct_b   = (const float*)d_in[5];
    const float* cs_w   = (const float*)d_in[6];
    const float* cs_b   = (const float*)d_in[7];
    const float* gcn_w  = (const float*)d_in[8];
    const float* gcn_b  = (const float*)d_in[9];
    const float* res_w  = (const float*)d_in[10];
    const float* res_b  = (const float*)d_in[11];
    const float* skip_w = (const float*)d_in[12];
    const float* skip_b = (const float*)d_in[13];
    const float* out1_w = (const float*)d_in[14];
    const float* out1_b = (const float*)d_in[15];
    const float* out2_w = (const float*)d_in[16];
    const float* out2_b = (const float*)d_in[17];

    _Float16* FR   = (_Float16*)d_ws;                 // 39936 f16 = 79872 B
    float*    BIAS = (float*)((char*)d_ws + 79872);   // 512 f32

    k_prep<<<158, 256, 0, stream>>>(A, in_w, in_b, ct_w, ct_b, cs_w, cs_b,
                                    gcn_w, res_w, skip_w, out1_w, out2_w,
                                    FR, BIAS);

    k_fused<<<8 * T_, 256, 0, stream>>>(X, FR, BIAS, in_b,
                                        gcn_b, res_b, skip_b,
                                        out1_b, out2_b, (float*)d_out);
}

// Round 8
// 198.135 us; speedup vs baseline: 1.3108x; 1.0557x over previous
//
#include <hip/hip_runtime.h>
#include <math.h>

#define T_ 512

typedef _Float16 half8 __attribute__((ext_vector_type(8)));
typedef _Float16 half4 __attribute__((ext_vector_type(4)));
typedef float f32x4 __attribute__((ext_vector_type(4)));

// Folded gated activation. k_prep pre-scales the tanh-branch conv weights and
// biases by 2*log2(e) and the sigmoid-branch by log2(e), so
//   tanh(a)*sigm(b) = (exp2(a')-1)*exp2(b') / ((exp2(a')+1)*(exp2(b')+1))
// with a',b' straight out of the MFMA. 2x v_exp + single raw v_rcp; the
// log2e multiplies and the a+a add are gone (moved into k_prep).
__device__ __forceinline__ float ts_act2(float a, float b) {
    float e2a = __builtin_exp2f(a);
    float eb  = __builtin_exp2f(b);
    float num = (e2a - 1.0f) * eb;
    float den = (e2a + 1.0f) * (eb + 1.0f);
    return num * __builtin_amdgcn_rcpf(den);
}

__device__ __forceinline__ half4 pack4(f32x4 v) {
    half4 h;
    h[0] = (_Float16)v[0]; h[1] = (_Float16)v[1];
    h[2] = (_Float16)v[2]; h[3] = (_Float16)v[3];
    return h;
}

// ---------------------------------------------------------------------------
// Prep fragment buffers in d_ws.
//  AF  [16384 f16] : adjacency, frag((it*4+kt))[lane][j] = A[it*16+(L&15)][kt*32+(L>>4)*8+j]
//  W32 [ 8192 f16] : K=32 folded conv mats (l*2+branch), 0..7 — PRE-SCALED by
//                    2*log2e (branch 0 / tanh) or log2e (branch 1 / sigm)
//  W16 [15360 f16] : K=16 mats: l*3+{0:gw,1:rw,2:sw} (0..11), 12:w1, 13:w2(pad), 14:winit16
//  BIAS[512 f32]   : pv-resolved conv biases (same pre-scaling): [(l*2+pv)*2+br]*32+n
// total idx = 16384+8192+15360+512 = 40448 = 158*256 (bytes: 79872 + 2048 = 81920)
// ---------------------------------------------------------------------------
__global__ __launch_bounds__(256) void k_prep(
    const float* __restrict__ A,     const float* __restrict__ in_w,
    const float* __restrict__ in_b,
    const float* __restrict__ ct_w,  const float* __restrict__ ct_b,
    const float* __restrict__ cs_w,  const float* __restrict__ cs_b,
    const float* __restrict__ gcn_w, const float* __restrict__ res_w,
    const float* __restrict__ skip_w,
    const float* __restrict__ out1_w,const float* __restrict__ out2_w,
    _Float16* __restrict__ FR, float* __restrict__ BIAS)
{
    int idx = blockIdx.x * 256 + threadIdx.x;
    if (idx < 16384) {
        int j = idx & 7, L = (idx >> 3) & 63, tile = idx >> 9;
        int it = tile >> 2, kt = tile & 3;
        FR[idx] = (_Float16)A[(it * 16 + (L & 15)) * 128 + kt * 32 + (L >> 4) * 8 + j];
    } else if (idx < 24576) {
        int e = idx - 16384;
        int j = e & 7, L = (e >> 3) & 63, ct = (e >> 9) & 1, mat = e >> 10;   // 0..7
        int k = (L >> 4) * 8 + j, col = ct * 16 + (L & 15);
        int l = mat >> 1, br = mat & 1;
        const float* tw = (br ? cs_w : ct_w) + l * 2048;
        int bro = br * 32;
        float v = 0.f;
        if (k < 16) { for (int c = 0; c < 32; ++c) v += in_w[k*96 + bro + c] * tw[c*32 + col]; }
        else        { for (int c = 0; c < 32; ++c) v += in_w[(k-16)*96 + bro + c] * tw[1024 + c*32 + col]; }
        v *= (br ? 1.4426950408889634f : 2.8853900817779268f);   // exp2 folding
        FR[idx] = (_Float16)v;
    } else if (idx < 39936) {
        int e = idx - 24576;
        int i = e & 3, L = (e >> 2) & 63, ct = (e >> 8) & 1, ks = (e >> 9) & 1, mat = e >> 10; // 0..14
        int k = ks * 16 + (L >> 4) * 4 + i, col = ct * 16 + (L & 15);
        float v;
        if (mat < 12) {
            int l = mat / 3, r = mat - l * 3;
            const float* W = (r == 0) ? gcn_w : (r == 1) ? res_w : skip_w;
            v = W[l * 1024 + k * 32 + col];
        } else if (mat == 12) v = out1_w[k * 32 + col];
        else if (mat == 13)   v = (ct == 0) ? out2_w[k * 16 + (L & 15)] : 0.f;
        else                  v = (ks == 0) ? in_w[k * 96 + 64 + col] : 0.f;   // winit K=16
        FR[idx] = (_Float16)v;
    } else if (idx < 40448) {
        // pv-resolved conv biases: e = l*128 + pvi*64 + br*32 + n
        int e = idx - 39936;
        int n = e & 31, br = (e >> 5) & 1, pvi = (e >> 6) & 1, l = e >> 7;
        const float* W  = br ? cs_w : ct_w;
        const float* bb = br ? cs_b : ct_b;
        int ibo = br * 32;
        float v = bb[l * 32 + n];
        for (int c = 0; c < 32; ++c) v += in_b[ibo + c] * W[l*2048 + 1024 + c*32 + n]; // cur tap
        if (pvi)
            for (int c = 0; c < 32; ++c) v += in_b[ibo + c] * W[l*2048 + c*32 + n];    // prev tap
        BIAS[e] = v * (br ? 1.4426950408889634f : 2.8853900817779268f);    // exp2 folding
    }
}

// ---------------------------------------------------------------------------
// Fused net. One block per (b,t), XCD-swizzled so XCD j owns batch j (X slab
// fits its 4MB L2). All 5 conv slabs (4 prev + cur) pre-staged into Pld in
// one load burst at block start -> zero global X traffic inside the loop.
// Layer body: publish -> barrier -> conv MFMA || A-mix MFMA || act VALU.
// R3 structure exactly (best measured); single change vs R3: exp2-folded
// activation (R7's other bundle members — full unroll, cvt_pkrtz packs,
// hoisted Afr — measured +29% VALU cycles combined and are reverted).
// ---------------------------------------------------------------------------
__global__ __launch_bounds__(256, 3) void k_fused(
    const float* __restrict__ X,
    const _Float16* __restrict__ FR,
    const float* __restrict__ BIAS,
    const float* __restrict__ in_b,
    const float* __restrict__ gcn_b,
    const float* __restrict__ res_b,
    const float* __restrict__ skip_b,
    const float* __restrict__ b1,
    const float* __restrict__ b2,
    float* __restrict__ out)
{
    __shared__ _Float16 Pld[128 * 88];        // [node][p0|p1|p2|p3|cur|pad8], stride 88
    __shared__ _Float16 xsT[2][32 * 136];     // [chan][node(128)+pad8], ping-pong

    const int bx = blockIdx.x;
    const int btid = ((bx & 7) << 9) | (bx >> 3);   // XCD j <- batch j
    const int b = btid >> 9, t = btid & (T_ - 1);
    const int tid = threadIdx.x, lane = tid & 63, w = tid >> 6;
    const int lm = lane & 15, kb = lane >> 4;
    const int R = w * 32;
    const int row = lane >> 1, ch = lane & 1;

    const half8* AFv  = (const half8*)FR;
    const half8* W32v = (const half8*)(FR + 16384);
    const half4* W16v = (const half4*)(FR + 24576);
    const f32x4 zero4 = {0.f, 0.f, 0.f, 0.f};

    // ---- stage ALL conv slabs up-front (one load burst, max MLP) ----
    {
        const size_t nrow = (size_t)(b * 128 + R + row) * T_;
        const float4* xc = (const float4*)(X + (nrow + t) * 16 + ch * 8);
        float4 c0 = xc[0], c1 = xc[1];
        float4 p0[4], p1[4];
#pragma unroll
        for (int l = 0; l < 4; ++l) {
            const int d = 1 << l;
            if (t >= d) {
                const float4* xp = (const float4*)(X + (nrow + (t - d)) * 16 + ch * 8);
                p0[l] = xp[0]; p1[l] = xp[1];
            } else {
                p0[l] = make_float4(0.f, 0.f, 0.f, 0.f);
                p1[l] = make_float4(0.f, 0.f, 0.f, 0.f);
            }
        }
        half8 hv;
        hv[0]=(_Float16)c0.x; hv[1]=(_Float16)c0.y; hv[2]=(_Float16)c0.z; hv[3]=(_Float16)c0.w;
        hv[4]=(_Float16)c1.x; hv[5]=(_Float16)c1.y; hv[6]=(_Float16)c1.z; hv[7]=(_Float16)c1.w;
        *(half8*)&Pld[(R + row) * 88 + 64 + ch * 8] = hv;
#pragma unroll
        for (int l = 0; l < 4; ++l) {
            hv[0]=(_Float16)p0[l].x; hv[1]=(_Float16)p0[l].y; hv[2]=(_Float16)p0[l].z; hv[3]=(_Float16)p0[l].w;
            hv[4]=(_Float16)p1[l].x; hv[5]=(_Float16)p1[l].y; hv[6]=(_Float16)p1[l].z; hv[7]=(_Float16)p1[l].w;
            *(half8*)&Pld[(R + row) * 88 + l * 16 + ch * 8] = hv;
        }
    }

    // ---- xres init: K=16 MFMA straight from registers (true coords) ----
    f32x4 xm[2][2], skT[2][2];
    {
        const float4 x0 = *(const float4*)(X + ((size_t)btid * 128 + R + lm) * 16 + kb * 4);
        const float4 x1 = *(const float4*)(X + ((size_t)btid * 128 + R + 16 + lm) * 16 + kb * 4);
        half4 p0, p1;
        p0[0]=(_Float16)x0.x; p0[1]=(_Float16)x0.y; p0[2]=(_Float16)x0.z; p0[3]=(_Float16)x0.w;
        p1[0]=(_Float16)x1.x; p1[1]=(_Float16)x1.y; p1[2]=(_Float16)x1.z; p1[3]=(_Float16)x1.w;
#pragma unroll
        for (int f = 0; f < 2; ++f) {
            half4 wi = W16v[(56 + f) * 64 + lane];          // winit mat 14, ks=0
            float bi = in_b[64 + f * 16 + lm];
            f32x4 cb; cb[0] = bi; cb[1] = bi; cb[2] = bi; cb[3] = bi;
            xm[0][f] = __builtin_amdgcn_mfma_f32_16x16x16f16(p0, wi, cb, 0, 0, 0);
            xm[1][f] = __builtin_amdgcn_mfma_f32_16x16x16f16(p1, wi, cb, 0, 0, 0);
        }
        // skip accumulator starts at sum_l skip_b (replaces per-layer adds)
#pragma unroll
        for (int f3 = 0; f3 < 2; ++f3) {
            f32x4 s = zero4;
#pragma unroll
            for (int l = 0; l < 4; ++l) {
                const float4 q = *(const float4*)&skip_b[l * 32 + f3 * 16 + kb * 4];
                s[0] += q.x; s[1] += q.y; s[2] += q.z; s[3] += q.w;
            }
            skT[f3][0] = s; skT[f3][1] = s;
        }
    }

    // per-lane conv fragment offset: kb<2 -> prev slab l (halves l*16+kb*8),
    // kb>=2 -> cur slab (halves 64+(kb-2)*8)
    const int fragoff = (kb < 2) ? kb * 8 : 64 + (kb - 2) * 8;
    const int lstep   = (kb < 2) ? 16 : 0;

#pragma unroll 1
    for (int l = 0; l < 4; ++l) {
        const bool pv = (t >= (1 << l));          // block-uniform
        const float* B2 = BIAS + (l * 2 + (pv ? 1 : 0)) * 64;
        const int buf = l & 1;

        // ---- publish xres (normal D -> chan-major LDS) ----
#pragma unroll
        for (int mt = 0; mt < 2; ++mt)
#pragma unroll
            for (int f = 0; f < 2; ++f)
                *(half4*)&xsT[buf][(f * 16 + lm) * 136 + R + mt * 16 + kb * 4] = pack4(xm[mt][f]);

        // ---- prefetch (latency drains at the barrier) ----
        half8 Afr[2][4];
#pragma unroll
        for (int mt = 0; mt < 2; ++mt)
#pragma unroll
            for (int kt = 0; kt < 4; ++kt)
                Afr[mt][kt] = AFv[((w * 2 + mt) * 4 + kt) * 64 + lane];
        const f32x4 cT0 = *(const f32x4*)&B2[0 * 16 + kb * 4];
        const f32x4 cT1 = *(const f32x4*)&B2[1 * 16 + kb * 4];
        const f32x4 cS0 = *(const f32x4*)&B2[32 + 0 * 16 + kb * 4];
        const f32x4 cS1 = *(const f32x4*)&B2[32 + 1 * 16 + kb * 4];

        __syncthreads();

        // ---- conv MFMAs (raw outputs kept; act deferred past A-mix) ----
        const int poff = fragoff + l * lstep;
        half8 pf0 = *(const half8*)&Pld[(R + lm) * 88 + poff];
        half8 pf1 = *(const half8*)&Pld[(R + 16 + lm) * 88 + poff];
        f32x4 dt[2][2], ds[2][2];                 // [ct][mt]
#pragma unroll
        for (int ct = 0; ct < 2; ++ct) {
            half8 wt = W32v[((l * 2 + 0) * 2 + ct) * 64 + lane];
            half8 ws = W32v[((l * 2 + 1) * 2 + ct) * 64 + lane];
            const f32x4 cT = ct ? cT1 : cT0;
            const f32x4 cS = ct ? cS1 : cS0;
            dt[ct][0] = __builtin_amdgcn_mfma_f32_16x16x32_f16(wt, pf0, cT, 0, 0, 0);
            dt[ct][1] = __builtin_amdgcn_mfma_f32_16x16x32_f16(wt, pf1, cT, 0, 0, 0);
            ds[ct][0] = __builtin_amdgcn_mfma_f32_16x16x32_f16(ws, pf0, cS, 0, 0, 0);
            ds[ct][1] = __builtin_amdgcn_mfma_f32_16x16x32_f16(ws, pf1, cS, 0, 0, 0);
        }

        // ---- A-mix: AxT[c][i] — A = xres^T frags (LDS), B = adjacency frags ----
        f32x4 AxT[2][2];                          // [f][mt]
#pragma unroll
        for (int f = 0; f < 2; ++f) {
            half8 xa[4];
#pragma unroll
            for (int kt = 0; kt < 4; ++kt)
                xa[kt] = *(const half8*)&xsT[buf][(f * 16 + lm) * 136 + kt * 32 + kb * 8];
#pragma unroll
            for (int mt = 0; mt < 2; ++mt) {
                f32x4 acc = zero4;
#pragma unroll
                for (int kt = 0; kt < 4; ++kt)
                    acc = __builtin_amdgcn_mfma_f32_16x16x32_f16(xa[kt], Afr[mt][kt], acc, 0, 0, 0);
                AxT[f][mt] = acc;
            }
        }

        // ---- act (exp2 chain overlaps A-mix MFMAs above) ----
        f32x4 tcv[2][2];                          // [ct][mt]
#pragma unroll
        for (int ct = 0; ct < 2; ++ct)
#pragma unroll
            for (int mt = 0; mt < 2; ++mt)
#pragma unroll
                for (int r = 0; r < 4; ++r)
                    tcv[ct][mt][r] = ts_act2(dt[ct][mt][r], ds[ct][mt][r]);

        // ---- gcn_T: gcn_b rides C; add tcv after ----
        half4 axh[2][2];
#pragma unroll
        for (int f = 0; f < 2; ++f)
#pragma unroll
            for (int mt = 0; mt < 2; ++mt) axh[f][mt] = pack4(AxT[f][mt]);
        half4 hh[2][2];                           // h_T packed [g][mt]
#pragma unroll
        for (int g = 0; g < 2; ++g) {
            half4 gw0 = W16v[((l * 3 + 0) * 4 + 0 + g) * 64 + lane];
            half4 gw1 = W16v[((l * 3 + 0) * 4 + 2 + g) * 64 + lane];
            const f32x4 gq = *(const f32x4*)&gcn_b[l * 32 + g * 16 + kb * 4];
#pragma unroll
            for (int mt = 0; mt < 2; ++mt) {
                f32x4 acc = __builtin_amdgcn_mfma_f32_16x16x16f16(gw0, axh[0][mt], gq, 0, 0, 0);
                acc = __builtin_amdgcn_mfma_f32_16x16x16f16(gw1, axh[1][mt], acc, 0, 0, 0);
#pragma unroll
                for (int r = 0; r < 4; ++r) acc[r] += tcv[g][mt][r];
                hh[g][mt] = pack4(acc);
            }
        }

        // ---- res (normal) & skip_T (bias pre-folded into skT init) ----
#pragma unroll
        for (int mt = 0; mt < 2; ++mt)
#pragma unroll
            for (int f3 = 0; f3 < 2; ++f3) {
                half4 rw0 = W16v[((l * 3 + 1) * 4 + 0 + f3) * 64 + lane];
                half4 rw1 = W16v[((l * 3 + 1) * 4 + 2 + f3) * 64 + lane];
                f32x4 acc = __builtin_amdgcn_mfma_f32_16x16x16f16(hh[0][mt], rw0, xm[mt][f3], 0, 0, 0);
                xm[mt][f3] = __builtin_amdgcn_mfma_f32_16x16x16f16(hh[1][mt], rw1, acc, 0, 0, 0);
                float rb = res_b[l * 32 + f3 * 16 + lm];
#pragma unroll
                for (int r = 0; r < 4; ++r) xm[mt][f3][r] += rb;

                half4 sw0 = W16v[((l * 3 + 2) * 4 + 0 + f3) * 64 + lane];
                half4 sw1 = W16v[((l * 3 + 2) * 4 + 2 + f3) * 64 + lane];
                f32x4 acs = __builtin_amdgcn_mfma_f32_16x16x16f16(sw0, hh[0][mt], skT[f3][mt], 0, 0, 0);
                skT[f3][mt] = __builtin_amdgcn_mfma_f32_16x16x16f16(sw1, hh[1][mt], acs, 0, 0, 0);
            }
    }

    // ---- output head (biases ride C operands) ----
    half4 rs[2][2];
#pragma unroll
    for (int g = 0; g < 2; ++g)
#pragma unroll
        for (int mt = 0; mt < 2; ++mt) {
            f32x4 v;
#pragma unroll
            for (int r = 0; r < 4; ++r) v[r] = fmaxf(skT[g][mt][r], 0.f);
            rs[g][mt] = pack4(v);
        }
    half4 h1h[2][2];
#pragma unroll
    for (int g4 = 0; g4 < 2; ++g4) {
        half4 w10 = W16v[(48 + 0 + g4) * 64 + lane];
        half4 w11 = W16v[(48 + 2 + g4) * 64 + lane];
        const f32x4 bq = *(const f32x4*)&b1[g4 * 16 + kb * 4];
#pragma unroll
        for (int mt = 0; mt < 2; ++mt) {
            f32x4 acc = __builtin_amdgcn_mfma_f32_16x16x16f16(w10, rs[0][mt], bq, 0, 0, 0);
            acc = __builtin_amdgcn_mfma_f32_16x16x16f16(w11, rs[1][mt], acc, 0, 0, 0);
            f32x4 v;
#pragma unroll
            for (int r = 0; r < 4; ++r) v[r] = fmaxf(acc[r], 0.f);
            h1h[g4][mt] = pack4(v);
        }
    }
    {
        half4 w20 = W16v[(52 + 0) * 64 + lane];
        half4 w21 = W16v[(52 + 2) * 64 + lane];
        const f32x4 b2q = *(const f32x4*)&b2[kb * 4];
#pragma unroll
        for (int mt = 0; mt < 2; ++mt) {
            f32x4 acc = __builtin_amdgcn_mfma_f32_16x16x16f16(w20, h1h[0][mt], b2q, 0, 0, 0);
            acc = __builtin_amdgcn_mfma_f32_16x16x16f16(w21, h1h[1][mt], acc, 0, 0, 0);
            float4 o = make_float4(acc[0], acc[1], acc[2], acc[3]);
            *(float4*)&out[((size_t)btid * 128 + R + mt * 16 + lm) * 16 + kb * 4] = o;
        }
    }
}

// ---------------------------------------------------------------------------
extern "C" void kernel_launch(void* const* d_in, const int* in_sizes, int n_in,
                              void* d_out, int out_size, void* d_ws, size_t ws_size,
                              hipStream_t stream)
{
    const float* X      = (const float*)d_in[0];
    const float* A      = (const float*)d_in[1];
    const float* in_w   = (const float*)d_in[2];
    const float* in_b   = (const float*)d_in[3];
    const float* ct_w   = (const float*)d_in[4];
    const float* ct_b   = (const float*)d_in[5];
    const float* cs_w   = (const float*)d_in[6];
    const float* cs_b   = (const float*)d_in[7];
    const float* gcn_w  = (const float*)d_in[8];
    const float* gcn_b  = (const float*)d_in[9];
    const float* res_w  = (const float*)d_in[10];
    const float* res_b  = (const float*)d_in[11];
    const float* skip_w = (const float*)d_in[12];
    const float* skip_b = (const float*)d_in[13];
    const float* out1_w = (const float*)d_in[14];
    const float* out1_b = (const float*)d_in[15];
    const float* out2_w = (const float*)d_in[16];
    const float* out2_b = (const float*)d_in[17];

    _Float16* FR   = (_Float16*)d_ws;                 // 39936 f16 = 79872 B
    float*    BIAS = (float*)((char*)d_ws + 79872);   // 512 f32

    k_prep<<<158, 256, 0, stream>>>(A, in_w, in_b, ct_w, ct_b, cs_w, cs_b,
                                    gcn_w, res_w, skip_w, out1_w, out2_w,
                                    FR, BIAS);

    k_fused<<<8 * T_, 256, 0, stream>>>(X, FR, BIAS, in_b,
                                        gcn_b, res_b, skip_b,
                                        out1_b, out2_b, (float*)d_out);
}